// Round 12
// baseline (5172.506 us; speedup 1.0000x reference)
//
#include <hip/hip_runtime.h>

typedef _Float16 f16x8 __attribute__((ext_vector_type(8)));
typedef float f32x4 __attribute__((ext_vector_type(4)));

#define LOG2E  1.44269504088896340736f
#define HS     72                  // f16 stride of h LDS rows
#define PBUF   (16*HS + 8)         // per-part elements incl 8-f16 zero pad
#define INV2K  4.8828125e-4f       // 2^-11
#define SC2K   2048.0f             // 2^11
#define INV4M  2.384185791015625e-7f  // 2^-22
#define SC4M   4194304.0f          // 2^22

struct F16p { _Float16 hi, lo; };
struct F16t { _Float16 h, l1, l2; };

__device__ __forceinline__ F16p split2(float x) {
    F16p o;
    o.hi = (_Float16)x;
    o.lo = (_Float16)((x - (float)o.hi) * SC2K);
    return o;
}
__device__ __forceinline__ F16t split3(float x) {
    F16t o;
    o.h = (_Float16)x;
    float d1 = x - (float)o.h;
    o.l1 = (_Float16)(d1 * SC2K);
    float d2 = __builtin_fmaf(-(float)o.l1, INV2K, d1);
    o.l2 = (_Float16)(d2 * SC4M);
    return o;
}

#define MFMA16(A,B,C) __builtin_amdgcn_mfma_f32_16x16x32_f16((A),(B),(C),0,0,0)

// Wave-autonomous GRU, z-dot folded into MFMA K-extension. Zero barriers.
__global__ __launch_bounds__(256, 1)
void gru_mfma_kernel(const float* __restrict__ z0,
                     const float* __restrict__ dtp,
                     const int* __restrict__ stepsp,
                     const float* __restrict__ Wih,
                     const float* __restrict__ Whh,
                     const float* __restrict__ bih,
                     const float* __restrict__ bhh,
                     const float* __restrict__ Whead,
                     const float* __restrict__ bhead,
                     float* __restrict__ out)
{
    // per-wave private A-matrix: parts {hi, lo1, lo2}; rows=16 elems, cols 0..63=h,
    // 64..66=z, 67=1.0, 68..71=0; + 8-f16 zero pad (for g>0 ext reads)
    __shared__ _Float16 hls[4][3][PBUF];

    const int tid = threadIdx.x;
    const int w   = tid >> 6;
    const int l   = tid & 63;
    const int c16 = l & 15;
    const int g   = l >> 4;

    const float dtv = dtp[0];
    const int nsteps = stepsp[0];
    const size_t T3 = (size_t)(nsteps + 1) * 3;
    const long blk = blockIdx.x;
    const int base_e = (int)blk*64 + w*16;

    // ---- W_hh B-frags (all 4 N-tiles), LOG2E-prescaled (2LOG2E for n-gate) ----
    f16x8 WBh[3][2][4], WBl[3][2][4];
    #pragma unroll
    for (int gate = 0; gate < 3; ++gate) {
        const float gs = (gate == 2) ? 2.f*LOG2E : LOG2E;
        #pragma unroll
        for (int nt = 0; nt < 4; ++nt) {
            const float* row = Whh + (size_t)(gate*64 + 16*nt + c16) * 64;
            #pragma unroll
            for (int kk = 0; kk < 2; ++kk) {
                const float* p = row + 32*kk + 8*g;
                f16x8 bh_, bl_;
                #pragma unroll
                for (int j = 0; j < 8; ++j) {
                    F16p s = split2(gs * p[j]);
                    bh_[j] = s.hi; bl_[j] = s.lo;
                }
                WBh[gate][kk][nt] = bh_;
                WBl[gate][kk][nt] = bl_;
            }
        }
    }
    // ---- B-ext frags: tiles {r,u,i} x {hi,lo} x nt; cols k=64..67 = Wih|bias ----
    f16x8 BEh[3][4], BEl[3][4];
    {
        f16x8 zf = {0,0,0,0,0,0,0,0};
        #pragma unroll
        for (int tl = 0; tl < 3; ++tl)
            #pragma unroll
            for (int nt = 0; nt < 4; ++nt) { BEh[tl][nt] = zf; BEl[tl][nt] = zf; }
        if (g == 0) {
            #pragma unroll
            for (int nt = 0; nt < 4; ++nt) {
                const int unit = 16*nt + c16;
                float xr[4], xu[4], xi[4];
                #pragma unroll
                for (int j = 0; j < 3; ++j) {
                    xr[j] = LOG2E      * Wih[(0*64+unit)*3 + j];
                    xu[j] = LOG2E      * Wih[(1*64+unit)*3 + j];
                    xi[j] = 2.f*LOG2E  * Wih[(2*64+unit)*3 + j];
                }
                xr[3] = LOG2E     * (bih[0*64+unit] + bhh[0*64+unit]);
                xu[3] = LOG2E     * (bih[1*64+unit] + bhh[1*64+unit]);
                xi[3] = 2.f*LOG2E *  bih[2*64+unit];
                #pragma unroll
                for (int j = 0; j < 4; ++j) {
                    F16p sr = split2(xr[j]); BEh[0][nt][j] = sr.hi; BEl[0][nt][j] = sr.lo;
                    F16p su = split2(xu[j]); BEh[1][nt][j] = su.hi; BEl[1][nt][j] = su.lo;
                    F16p si = split2(xi[j]); BEh[2][nt][j] = si.hi; BEl[2][nt][j] = si.lo;
                }
            }
        }
    }
    // ---- head B-frags (plain scale; dt applied at update) ----
    f16x8 HBh[2], HBl[2];
    {
        f16x8 zf = {0,0,0,0,0,0,0,0};
        HBh[0]=zf; HBh[1]=zf; HBl[0]=zf; HBl[1]=zf;
        if (c16 < 3) {
            #pragma unroll
            for (int kk = 0; kk < 2; ++kk) {
                const float* p = Whead + (size_t)c16*64 + 32*kk + 8*g;
                f16x8 bh_, bl_;
                #pragma unroll
                for (int j = 0; j < 8; ++j) {
                    F16p s = split2(p[j]);
                    bh_[j] = s.hi; bl_[j] = s.lo;
                }
                HBh[kk] = bh_; HBl[kk] = bl_;
            }
        }
    }

    // ---- per-lane scalars: only n-gate hidden bias (2LOG2E-scaled) + head bias ----
    float bhnv[4];
    #pragma unroll
    for (int nt = 0; nt < 4; ++nt)
        bhnv[nt] = 2.f*LOG2E * bhh[2*64 + 16*nt + c16];
    float bhc = 0.f;
    if (c16 < 3) bhc = bhead[c16];

    // ---- z slice: lane (c16<3, g) owns z[elem 4g+r][c16] ----
    float zsl[4] = {0.f,0.f,0.f,0.f};
    if (c16 < 3) {
        #pragma unroll
        for (int r = 0; r < 4; ++r)
            zsl[r] = z0[(size_t)(base_e + 4*g + r)*3 + c16];
    }

    // ---- out cursor ----
    float* o0 = out;
    if (c16 < 3) {
        o0 = out + (size_t)(base_e + 4*g)*T3 + c16;
        #pragma unroll
        for (int r = 0; r < 4; ++r) o0[(size_t)r*T3] = zsl[r];
    }
    o0 += 3;   // -> t=1

    // step-invariant LDS element offsets
    const int adA0 = c16*HS + 8*g;                         // h chunks (+0, +32)
    const int adE  = (g == 0) ? (c16*HS + 64) : (16*HS);   // ext chunk / zero pad

    // ---- zero this wave's buffers (h=0, ext cols, pads) ----
    {
        uint* hz = (uint*)&hls[w][0][0];
        #pragma unroll
        for (int k = 0; k < (3*PBUF)/(2*64); ++k) hz[l + 64*k] = 0u;
        if (l < (3*PBUF/2) - 64*((3*PBUF)/(2*64))) hz[64*((3*PBUF)/(2*64)) + l] = 0u;
    }
    // ---- init ext columns: z0 (c16<3) and the 1.0 column (c16==3) ----
    if (c16 < 4) {
        #pragma unroll
        for (int r = 0; r < 4; ++r) {
            float v = (c16 < 3) ? zsl[r] : 1.0f;
            F16t s = split3(v);
            int ad = (4*g + r)*HS + 64 + c16;
            hls[w][0][ad] = s.h; hls[w][1][ad] = s.l1; hls[w][2][ad] = s.l2;
        }
    }

    float hC[4][4] = {{0,0,0,0},{0,0,0,0},{0,0,0,0},{0,0,0,0}};

#define GTILE(G_, NT_, A1, A2, A3) do {                                          \
    A1 = MFMA16(FAh0, WBh[G_][0][NT_], A1);                                      \
    A1 = MFMA16(FAh1, WBh[G_][1][NT_], A1);                                      \
    A1 = MFMA16(FAhE, BEh[G_][NT_],  A1);                                        \
    A2 = MFMA16(FAh0, WBl[G_][0][NT_], A2);                                      \
    A2 = MFMA16(FAl0, WBh[G_][0][NT_], A2);                                      \
    A2 = MFMA16(FAh1, WBl[G_][1][NT_], A2);                                      \
    A2 = MFMA16(FAl1, WBh[G_][1][NT_], A2);                                      \
    A2 = MFMA16(FAhE, BEl[G_][NT_],  A2);                                        \
    A2 = MFMA16(FAlE, BEh[G_][NT_],  A2);                                        \
    A3 = MFMA16(FAlE, BEl[G_][NT_],  A3);                                        \
    A3 = MFMA16(FAmE, BEh[G_][NT_],  A3);                                        \
} while (0)

#define STEP(DOZ) do {                                                           \
    f16x8 FAh0 = *(const f16x8*)&hls[w][0][adA0];                                \
    f16x8 FAh1 = *(const f16x8*)&hls[w][0][adA0 + 32];                           \
    f16x8 FAl0 = *(const f16x8*)&hls[w][1][adA0];                                \
    f16x8 FAl1 = *(const f16x8*)&hls[w][1][adA0 + 32];                           \
    if (DOZ) {                                                                   \
        f32x4 ha = {0.f,0.f,0.f,0.f}, hb = {0.f,0.f,0.f,0.f};                    \
        ha = MFMA16(FAh0, HBh[0], ha); ha = MFMA16(FAh1, HBh[1], ha);            \
        hb = MFMA16(FAh0, HBl[0], hb); hb = MFMA16(FAl0, HBh[0], hb);            \
        hb = MFMA16(FAh1, HBl[1], hb); hb = MFMA16(FAl1, HBh[1], hb);            \
        if (c16 < 3) {                                                           \
            _Pragma("unroll")                                                    \
            for (int r = 0; r < 4; ++r) {                                        \
                float fv = __builtin_fmaf(INV2K, hb[r], ha[r]) + bhc;            \
                zsl[r] = __builtin_fmaf(dtv, fv, zsl[r]);                        \
                o0[(size_t)r*T3] = zsl[r];                                       \
                F16t s = split3(zsl[r]);                                         \
                int ad = (4*g + r)*HS + 64 + c16;                                \
                hls[w][0][ad] = s.h; hls[w][1][ad] = s.l1; hls[w][2][ad] = s.l2; \
            }                                                                    \
        }                                                                        \
        o0 += 3;                                                                 \
    }                                                                            \
    f16x8 FAhE = *(const f16x8*)&hls[w][0][adE];                                 \
    f16x8 FAlE = *(const f16x8*)&hls[w][1][adE];                                 \
    f16x8 FAmE = *(const f16x8*)&hls[w][2][adE];                                 \
    _Pragma("unroll")                                                            \
    for (int nt = 0; nt < 4; ++nt) {                                             \
        f32x4 zz = {0.f,0.f,0.f,0.f};                                            \
        f32x4 a1r=zz,a2r=zz,a3r=zz, a1u=zz,a2u=zz,a3u=zz;                        \
        f32x4 a1n=zz,a2n=zz, a1i=zz,a2i=zz,a3i=zz;                               \
        GTILE(0, nt, a1r, a2r, a3r);                                             \
        GTILE(1, nt, a1u, a2u, a3u);                                             \
        a1n = MFMA16(FAh0, WBh[2][0][nt], a1n);                                  \
        a1n = MFMA16(FAh1, WBh[2][1][nt], a1n);                                  \
        a2n = MFMA16(FAh0, WBl[2][0][nt], a2n);                                  \
        a2n = MFMA16(FAl0, WBh[2][0][nt], a2n);                                  \
        a2n = MFMA16(FAh1, WBl[2][1][nt], a2n);                                  \
        a2n = MFMA16(FAl1, WBh[2][1][nt], a2n);                                  \
        a1i = MFMA16(FAhE, BEh[2][nt], a1i);                                     \
        a2i = MFMA16(FAhE, BEl[2][nt], a2i);                                     \
        a2i = MFMA16(FAlE, BEh[2][nt], a2i);                                     \
        a3i = MFMA16(FAlE, BEl[2][nt], a3i);                                     \
        a3i = MFMA16(FAmE, BEh[2][nt], a3i);                                     \
        _Pragma("unroll")                                                        \
        for (int r = 0; r < 4; ++r) {                                            \
            float ars = __builtin_fmaf(INV2K, a2r[r], a1r[r]);                   \
            ars = __builtin_fmaf(INV4M, a3r[r], ars);                            \
            float aus = __builtin_fmaf(INV2K, a2u[r], a1u[r]);                   \
            aus = __builtin_fmaf(INV4M, a3u[r], aus);                            \
            float anh = __builtin_fmaf(INV2K, a2n[r], a1n[r]) + bhnv[nt];        \
            float ain = __builtin_fmaf(INV2K, a2i[r], a1i[r]);                   \
            ain = __builtin_fmaf(INV4M, a3i[r], ain);                            \
            float rg = __builtin_amdgcn_rcpf(1.f + __builtin_amdgcn_exp2f(-ars));\
            float ug = __builtin_amdgcn_rcpf(1.f + __builtin_amdgcn_exp2f(-aus));\
            float xs = __builtin_fmaf(rg, anh, ain);                             \
            float ng = __builtin_fmaf(-2.f,                                      \
                __builtin_amdgcn_rcpf(1.f + __builtin_amdgcn_exp2f(xs)), 1.f);   \
            float hn = __builtin_fmaf(ug, hC[nt][r] - ng, ng);                   \
            hC[nt][r] = hn;                                                      \
            F16p s = split2(hn);                                                 \
            int ad = (4*g + r)*HS + 16*nt + c16;                                 \
            hls[w][0][ad] = s.hi; hls[w][1][ad] = s.lo;                          \
        }                                                                        \
    }                                                                            \
} while (0)

    // ---- main loop: zero barriers (wave-private LDS, in-order DS pipe) ----
    STEP(false);
    #pragma unroll 1
    for (int t = 1; t < nsteps; ++t) STEP(true);

    // ---- epilogue: z(nsteps) from head over h(nsteps) ----
    {
        f16x8 FAh0 = *(const f16x8*)&hls[w][0][adA0];
        f16x8 FAh1 = *(const f16x8*)&hls[w][0][adA0 + 32];
        f16x8 FAl0 = *(const f16x8*)&hls[w][1][adA0];
        f16x8 FAl1 = *(const f16x8*)&hls[w][1][adA0 + 32];
        f32x4 ha = {0.f,0.f,0.f,0.f}, hb = {0.f,0.f,0.f,0.f};
        ha = MFMA16(FAh0, HBh[0], ha); ha = MFMA16(FAh1, HBh[1], ha);
        hb = MFMA16(FAh0, HBl[0], hb); hb = MFMA16(FAl0, HBh[0], hb);
        hb = MFMA16(FAh1, HBl[1], hb); hb = MFMA16(FAl1, HBh[1], hb);
        if (c16 < 3) {
            #pragma unroll
            for (int r = 0; r < 4; ++r) {
                float fv = __builtin_fmaf(INV2K, hb[r], ha[r]) + bhc;
                zsl[r] = __builtin_fmaf(dtv, fv, zsl[r]);
                o0[(size_t)r*T3] = zsl[r];
            }
        }
    }
#undef STEP
#undef GTILE
}

extern "C" void kernel_launch(void* const* d_in, const int* in_sizes, int n_in,
                              void* d_out, int out_size, void* d_ws, size_t ws_size,
                              hipStream_t stream) {
    const float* z0    = (const float*)d_in[0];
    const float* dtp   = (const float*)d_in[1];
    const int*   steps = (const int*)  d_in[2];
    const float* Wih   = (const float*)d_in[3];
    const float* Whh   = (const float*)d_in[4];
    const float* bih   = (const float*)d_in[5];
    const float* bhh   = (const float*)d_in[6];
    const float* Whead = (const float*)d_in[7];
    const float* bhead = (const float*)d_in[8];
    float* out = (float*)d_out;

    const int B = in_sizes[0] / 3;          // 16384
    const int nblk = B / 64;                // 256 blocks x 4 waves = 1 wave/SIMD

    hipLaunchKernelGGL(gru_mfma_kernel, dim3(nblk), dim3(256), 0, stream,
                       z0, dtp, steps, Wih, Whh, bih, bhh, Whead, bhead, out);
}

// Round 13
// 4467.094 us; speedup vs baseline: 1.1579x; 1.1579x over previous
//
#include <hip/hip_runtime.h>

typedef _Float16 f16x8 __attribute__((ext_vector_type(8)));
typedef float f32x4 __attribute__((ext_vector_type(4)));

#define LOG2E 1.44269504088896340736f
#define MELEM 32          // batch elems per block (2 M-tiles of 16)
#define HS 72             // f16 stride of h LDS rows (16B-aligned, bank-spread)
#define INV2K 4.8828125e-4f   // 2^-11
#define SC2K  2048.0f         // 2^11

__device__ __forceinline__ float bpermf(int sa, float v) {
    return __builtin_bit_cast(float,
        __builtin_amdgcn_ds_bpermute(sa, __builtin_bit_cast(int, v)));
}

__global__ __launch_bounds__(256, 2)
void gru_mfma_kernel(const float* __restrict__ z0,
                     const float* __restrict__ dtp,
                     const int* __restrict__ stepsp,
                     const float* __restrict__ Wih,
                     const float* __restrict__ Whh,
                     const float* __restrict__ bih,
                     const float* __restrict__ bhh,
                     const float* __restrict__ Whead,
                     const float* __restrict__ bhead,
                     float* __restrict__ out)
{
    // [pingpong][part hi/lo][elem*HS + unit], fp16 2-way split of h
    __shared__ _Float16 hbuf[2][2][MELEM*HS];

    const int tid = threadIdx.x;
    const int w   = tid >> 6;       // wave 0..3 -> unit range [16w,16w+16)
    const int l   = tid & 63;
    const int c16 = l & 15;
    const int g   = l >> 4;         // 0..3
    const int unit = 16*w + c16;

    const float dtv = dtp[0];
    const int nsteps = stepsp[0];
    const size_t T3 = (size_t)(nsteps + 1) * 3;
    const long blk = blockIdx.x;

    // ---- B-fragments of W_hh: fp16 hi + 2^11-scaled lo, LOG2E-prescaled ----
    // gates r,u scaled by LOG2E; gate n by 2*LOG2E (tanh's 2x folded in)
    f16x8 WBh[3][2], WBl[3][2];
    #pragma unroll
    for (int gate = 0; gate < 3; ++gate) {
        const float gs = (gate == 2) ? 2.f*LOG2E : LOG2E;
        const float* row = Whh + (size_t)(gate*64 + unit) * 64;
        #pragma unroll
        for (int kk = 0; kk < 2; ++kk) {
            const float* p = row + 32*kk + 8*g;
            f16x8 bh_, bl_;
            #pragma unroll
            for (int j = 0; j < 8; ++j) {
                float x = gs * p[j];
                _Float16 hi = (_Float16)x;
                bh_[j] = hi;
                bl_[j] = (_Float16)((x - (float)hi) * SC2K);
            }
            WBh[gate][kk] = bh_;
            WBl[gate][kk] = bl_;
        }
    }
    // ---- head B-fragments in regs (cols >= 3 zero), plain scale ----
    f16x8 HBh[2], HBl[2];
    {
        f16x8 zf = {0,0,0,0,0,0,0,0};
        HBh[0]=zf; HBh[1]=zf; HBl[0]=zf; HBl[1]=zf;
        if (c16 < 3) {
            #pragma unroll
            for (int kk = 0; kk < 2; ++kk) {
                const float* p = Whead + (size_t)c16*64 + 32*kk + 8*g;
                f16x8 bh_, bl_;
                #pragma unroll
                for (int j = 0; j < 8; ++j) {
                    float x = p[j];
                    _Float16 hi = (_Float16)x;
                    bh_[j] = hi;
                    bl_[j] = (_Float16)((x - (float)hi) * SC2K);
                }
                HBh[kk] = bh_; HBl[kk] = bl_;
            }
        }
    }

    // ---- per-lane scalar weights / biases (prescaled) ----
    const float wir0 = LOG2E*Wih[(0*64+unit)*3+0], wir1 = LOG2E*Wih[(0*64+unit)*3+1], wir2 = LOG2E*Wih[(0*64+unit)*3+2];
    const float wiu0 = LOG2E*Wih[(1*64+unit)*3+0], wiu1 = LOG2E*Wih[(1*64+unit)*3+1], wiu2 = LOG2E*Wih[(1*64+unit)*3+2];
    const float win0 = 2.f*LOG2E*Wih[(2*64+unit)*3+0], win1 = 2.f*LOG2E*Wih[(2*64+unit)*3+1], win2 = 2.f*LOG2E*Wih[(2*64+unit)*3+2];
    const float br   = LOG2E*(bih[0*64+unit] + bhh[0*64+unit]);
    const float bu   = LOG2E*(bih[1*64+unit] + bhh[1*64+unit]);
    const float bin_ = 2.f*LOG2E*bih[2*64+unit];
    const float bhn  = 2.f*LOG2E*bhh[2*64+unit];
    float bhc = 0.f;
    if (c16 < 3) bhc = bhead[c16];

    // ---- z replicated in registers on every lane (all indices static) ----
    float zreg[2][4][3];
    #pragma unroll
    for (int mt = 0; mt < 2; ++mt)
        #pragma unroll
        for (int r = 0; r < 4; ++r)
            #pragma unroll
            for (int c = 0; c < 3; ++c)
                zreg[mt][r][c] = z0[(size_t)(blk*MELEM + mt*16 + 4*g + r)*3 + c];

    // ---- persistent traj cursors (designated lanes: w<2 && c16<3) ----
    float* o0 = out; float* o1 = out; float* o2 = out; float* o3 = out;
    if (w < 2 && c16 < 3) {
        size_t e0 = (size_t)(blk*MELEM + w*16 + 4*g);
        o0 = out + (e0+0)*T3 + c16;
        o1 = out + (e0+1)*T3 + c16;
        o2 = out + (e0+2)*T3 + c16;
        o3 = out + (e0+3)*T3 + c16;
    }
    // t=0 row (static zreg indices via unrolled predication)
    #pragma unroll
    for (int mt = 0; mt < 2; ++mt)
        #pragma unroll
        for (int c = 0; c < 3; ++c)
            if (w == mt && c16 == c) {
                o0[0] = zreg[mt][0][c]; o1[0] = zreg[mt][1][c];
                o2[0] = zreg[mt][2][c]; o3[0] = zreg[mt][3][c];
            }
    if (w < 2 && c16 < 3) { o0 += 3; o1 += 3; o2 += 3; o3 += 3; }  // -> t=1

    // hoisted bpermute byte-addresses
    const int sa0 = (l & 48) << 2;
    const int sa1 = sa0 + 4;
    const int sa2 = sa0 + 8;

    // step-invariant LDS element offset for A-fragments (row = c16)
    const int adA0 = c16*HS + 8*g;

    // ---- zero h buffer 0 (h_0 = 0) ----
    {
        uint* hz = (uint*)&hbuf[0][0][0];
        for (int i = tid; i < MELEM*HS; i += 256) hz[i] = 0u;
    }

    float hC[2][4] = {{0,0,0,0},{0,0,0,0}};

    __syncthreads();

#define GATE(GT, GR, BIAS) do {                                                  \
    f32x4 a1 = {BIAS,BIAS,BIAS,BIAS}, a2 = {0.f,0.f,0.f,0.f};                    \
    a1 = __builtin_amdgcn_mfma_f32_16x16x32_f16(FAh0, WBh[GT][0], a1, 0,0,0);    \
    a2 = __builtin_amdgcn_mfma_f32_16x16x32_f16(FAh0, WBl[GT][0], a2, 0,0,0);    \
    a2 = __builtin_amdgcn_mfma_f32_16x16x32_f16(FAl0, WBh[GT][0], a2, 0,0,0);    \
    a1 = __builtin_amdgcn_mfma_f32_16x16x32_f16(FAh1, WBh[GT][1], a1, 0,0,0);    \
    a2 = __builtin_amdgcn_mfma_f32_16x16x32_f16(FAh1, WBl[GT][1], a2, 0,0,0);    \
    a2 = __builtin_amdgcn_mfma_f32_16x16x32_f16(FAl1, WBh[GT][1], a2, 0,0,0);    \
    _Pragma("unroll")                                                            \
    for (int rr = 0; rr < 4; ++rr) GR[rr] = __builtin_fmaf(INV2K, a2[rr], a1[rr]); \
} while (0)

#define STEP(P, DOZ) do {                                                        \
    f16x8 FAh0 = *(const f16x8*)&hbuf[P][0][adA0];                               \
    f16x8 FAh1 = *(const f16x8*)&hbuf[P][0][adA0 + 32];                          \
    f16x8 FAl0 = *(const f16x8*)&hbuf[P][1][adA0];                               \
    f16x8 FAl1 = *(const f16x8*)&hbuf[P][1][adA0 + 32];                          \
    if (DOZ) {                                                                   \
        f32x4 ha = {bhc,bhc,bhc,bhc}, hb = {0.f,0.f,0.f,0.f};                    \
        ha = __builtin_amdgcn_mfma_f32_16x16x32_f16(FAh0, HBh[0], ha, 0,0,0);    \
        ha = __builtin_amdgcn_mfma_f32_16x16x32_f16(FAh1, HBh[1], ha, 0,0,0);    \
        hb = __builtin_amdgcn_mfma_f32_16x16x32_f16(FAh0, HBl[0], hb, 0,0,0);    \
        hb = __builtin_amdgcn_mfma_f32_16x16x32_f16(FAl0, HBh[0], hb, 0,0,0);    \
        hb = __builtin_amdgcn_mfma_f32_16x16x32_f16(FAh1, HBl[1], hb, 0,0,0);    \
        hb = __builtin_amdgcn_mfma_f32_16x16x32_f16(FAl1, HBh[1], hb, 0,0,0);    \
        _Pragma("unroll")                                                        \
        for (int r = 0; r < 4; ++r) {                                            \
            float fv = __builtin_fmaf(INV2K, hb[r], ha[r]);                      \
            zreg[r>>2][r][0] = 0.f; /* placeholder, never used */                \
        }                                                                        \
        _Pragma("unroll")                                                        \
        for (int mt = 0; mt < 2; ++mt)                                           \
            _Pragma("unroll")                                                    \
            for (int r = 0; r < 4; ++r) {                                        \
                float fv = (mt == 0) ? __builtin_fmaf(INV2K, hb[r], ha[r]) : 0.f;\
                (void)fv;                                                        \
            }                                                                    \
        o0 += 0;                                                                 \
    }                                                                            \
    __syncthreads();                                                             \
} while (0)

    // NOTE: STEP above is a stub — real step below (kept single definition).
#undef STEP

#define STEP(P, DOZ) do {                                                        \
    f16x8 FAh0 = *(const f16x8*)&hbuf[P][0][adA0];                               \
    f16x8 FAh1 = *(const f16x8*)&hbuf[P][0][adA0 + 32];                          \
    f16x8 FAl0 = *(const f16x8*)&hbuf[P][1][adA0];                               \
    f16x8 FAl1 = *(const f16x8*)&hbuf[P][1][adA0 + 32];                          \
    if (DOZ) {                                                                   \
        f32x4 ha[2], hb[2];                                                      \
        _Pragma("unroll")                                                        \
        for (int mt = 0; mt < 2; ++mt) {                                         \
            f32x4 a = {bhc,bhc,bhc,bhc}, b = {0.f,0.f,0.f,0.f};                  \
            if (mt == 0) {                                                       \
                a = __builtin_amdgcn_mfma_f32_16x16x32_f16(FAh0, HBh[0], a, 0,0,0); \
                a = __builtin_amdgcn_mfma_f32_16x16x32_f16(FAh1, HBh[1], a, 0,0,0); \
                b = __builtin_amdgcn_mfma_f32_16x16x32_f16(FAh0, HBl[0], b, 0,0,0); \
                b = __builtin_amdgcn_mfma_f32_16x16x32_f16(FAl0, HBh[0], b, 0,0,0); \
                b = __builtin_amdgcn_mfma_f32_16x16x32_f16(FAh1, HBl[1], b, 0,0,0); \
                b = __builtin_amdgcn_mfma_f32_16x16x32_f16(FAl1, HBh[1], b, 0,0,0); \
            } else {                                                             \
                a = __builtin_amdgcn_mfma_f32_16x16x32_f16(FBh0, HBh[0], a, 0,0,0); \
                a = __builtin_amdgcn_mfma_f32_16x16x32_f16(FBh1, HBh[1], a, 0,0,0); \
                b = __builtin_amdgcn_mfma_f32_16x16x32_f16(FBh0, HBl[0], b, 0,0,0); \
                b = __builtin_amdgcn_mfma_f32_16x16x32_f16(FBl0, HBh[0], b, 0,0,0); \
                b = __builtin_amdgcn_mfma_f32_16x16x32_f16(FBh1, HBl[1], b, 0,0,0); \
                b = __builtin_amdgcn_mfma_f32_16x16x32_f16(FBl1, HBh[1], b, 0,0,0); \
            }                                                                    \
            ha[mt] = a; hb[mt] = b;                                              \
        }                                                                        \
        _Pragma("unroll")                                                        \
        for (int mt = 0; mt < 2; ++mt)                                           \
            _Pragma("unroll")                                                    \
            for (int r = 0; r < 4; ++r) {                                        \
                float fv = __builtin_fmaf(INV2K, hb[mt][r], ha[mt][r]);          \
                zreg[mt][r][0] = __builtin_fmaf(dtv, bpermf(sa0, fv), zreg[mt][r][0]); \
                zreg[mt][r][1] = __builtin_fmaf(dtv, bpermf(sa1, fv), zreg[mt][r][1]); \
                zreg[mt][r][2] = __builtin_fmaf(dtv, bpermf(sa2, fv), zreg[mt][r][2]); \
            }                                                                    \
        _Pragma("unroll")                                                        \
        for (int mt = 0; mt < 2; ++mt)                                           \
            _Pragma("unroll")                                                    \
            for (int c = 0; c < 3; ++c)                                          \
                if (w == mt && c16 == c) {                                       \
                    o0[0] = zreg[mt][0][c]; o1[0] = zreg[mt][1][c];              \
                    o2[0] = zreg[mt][2][c]; o3[0] = zreg[mt][3][c];              \
                }                                                                \
        if (w < 2 && c16 < 3) { o0 += 3; o1 += 3; o2 += 3; o3 += 3; }            \
    }                                                                            \
    _Pragma("unroll")                                                            \
    for (int mt = 0; mt < 2; ++mt) {                                             \
        f32x4 gr0, gr1, gr2;                                                     \
        if (mt == 0) {                                                           \
            GATE0(0, gr0, br); GATE0(1, gr1, bu); GATE0(2, gr2, bhn);            \
        } else {                                                                 \
            GATE1(0, gr0, br); GATE1(1, gr1, bu); GATE1(2, gr2, bhn);            \
        }                                                                        \
        _Pragma("unroll")                                                        \
        for (int r = 0; r < 4; ++r) {                                            \
            float z0v = zreg[mt][r][0], z1v = zreg[mt][r][1], z2v = zreg[mt][r][2]; \
            float ar  = __builtin_fmaf(wir0, z0v, __builtin_fmaf(wir1, z1v,      \
                        __builtin_fmaf(wir2, z2v, gr0[r])));                     \
            float au  = __builtin_fmaf(wiu0, z0v, __builtin_fmaf(wiu1, z1v,      \
                        __builtin_fmaf(wiu2, z2v, gr1[r])));                     \
            float ain = __builtin_fmaf(win0, z0v, __builtin_fmaf(win1, z1v,      \
                        __builtin_fmaf(win2, z2v, bin_)));                       \
            float rg = __builtin_amdgcn_rcpf(1.f + __builtin_amdgcn_exp2f(-ar)); \
            float ug = __builtin_amdgcn_rcpf(1.f + __builtin_amdgcn_exp2f(-au)); \
            float xs = __builtin_fmaf(rg, gr2[r], ain);                          \
            float ng = __builtin_fmaf(-2.f,                                      \
                __builtin_amdgcn_rcpf(1.f + __builtin_amdgcn_exp2f(xs)), 1.f);   \
            float hn = __builtin_fmaf(ug, hC[mt][r] - ng, ng);                   \
            hC[mt][r] = hn;                                                      \
            _Float16 hi = (_Float16)hn;                                          \
            _Float16 lo = (_Float16)((hn - (float)hi) * SC2K);                   \
            hbuf[(P)^1][0][(mt*16 + 4*g + r)*HS + unit] = hi;                    \
            hbuf[(P)^1][1][(mt*16 + 4*g + r)*HS + unit] = lo;                    \
        }                                                                        \
    }                                                                            \
    __syncthreads();                                                             \
} while (0)

#define GATE0(GT, GR, BIAS) do {                                                 \
    f32x4 a1 = {BIAS,BIAS,BIAS,BIAS}, a2 = {0.f,0.f,0.f,0.f};                    \
    a1 = __builtin_amdgcn_mfma_f32_16x16x32_f16(FAh0, WBh[GT][0], a1, 0,0,0);    \
    a2 = __builtin_amdgcn_mfma_f32_16x16x32_f16(FAh0, WBl[GT][0], a2, 0,0,0);    \
    a2 = __builtin_amdgcn_mfma_f32_16x16x32_f16(FAl0, WBh[GT][0], a2, 0,0,0);    \
    a1 = __builtin_amdgcn_mfma_f32_16x16x32_f16(FAh1, WBh[GT][1], a1, 0,0,0);    \
    a2 = __builtin_amdgcn_mfma_f32_16x16x32_f16(FAh1, WBl[GT][1], a2, 0,0,0);    \
    a2 = __builtin_amdgcn_mfma_f32_16x16x32_f16(FAl1, WBh[GT][1], a2, 0,0,0);    \
    _Pragma("unroll")                                                            \
    for (int rr = 0; rr < 4; ++rr) GR[rr] = __builtin_fmaf(INV2K, a2[rr], a1[rr]); \
} while (0)
#define GATE1(GT, GR, BIAS) do {                                                 \
    f32x4 a1 = {BIAS,BIAS,BIAS,BIAS}, a2 = {0.f,0.f,0.f,0.f};                    \
    a1 = __builtin_amdgcn_mfma_f32_16x16x32_f16(FBh0, WBh[GT][0], a1, 0,0,0);    \
    a2 = __builtin_amdgcn_mfma_f32_16x16x32_f16(FBh0, WBl[GT][0], a2, 0,0,0);    \
    a2 = __builtin_amdgcn_mfma_f32_16x16x32_f16(FBl0, WBh[GT][0], a2, 0,0,0);    \
    a1 = __builtin_amdgcn_mfma_f32_16x16x32_f16(FBh1, WBh[GT][1], a1, 0,0,0);    \
    a2 = __builtin_amdgcn_mfma_f32_16x16x32_f16(FBh1, WBl[GT][1], a2, 0,0,0);    \
    a2 = __builtin_amdgcn_mfma_f32_16x16x32_f16(FBl1, WBh[GT][1], a2, 0,0,0);    \
    _Pragma("unroll")                                                            \
    for (int rr = 0; rr < 4; ++rr) GR[rr] = __builtin_fmaf(INV2K, a2[rr], a1[rr]); \
} while (0)

#define STEPFULL(P, DOZ) do {                                                    \
    f16x8 FAh0 = *(const f16x8*)&hbuf[P][0][adA0];                               \
    f16x8 FAh1 = *(const f16x8*)&hbuf[P][0][adA0 + 32];                          \
    f16x8 FAl0 = *(const f16x8*)&hbuf[P][1][adA0];                               \
    f16x8 FAl1 = *(const f16x8*)&hbuf[P][1][adA0 + 32];                          \
    f16x8 FBh0 = *(const f16x8*)&hbuf[P][0][adA0 + 16*HS];                       \
    f16x8 FBh1 = *(const f16x8*)&hbuf[P][0][adA0 + 16*HS + 32];                  \
    f16x8 FBl0 = *(const f16x8*)&hbuf[P][1][adA0 + 16*HS];                       \
    f16x8 FBl1 = *(const f16x8*)&hbuf[P][1][adA0 + 16*HS + 32];                  \
    STEP(P, DOZ);                                                                \
} while (0)

    // ---- main loop: peel t=0, then pairs (compile-time ping-pong) ----
    STEPFULL(0, false);
    int t = 1;
    for (; t + 1 < nsteps; t += 2) {
        STEPFULL(1, true);
        STEPFULL(0, true);
    }
    if (t < nsteps) { STEPFULL(1, true); ++t; }

    // ---- epilogue: z(nsteps) from head over h(nsteps) ----
    {
        const int P = nsteps & 1;
        f16x8 FAh0 = *(const f16x8*)&hbuf[P][0][adA0];
        f16x8 FAh1 = *(const f16x8*)&hbuf[P][0][adA0 + 32];
        f16x8 FAl0 = *(const f16x8*)&hbuf[P][1][adA0];
        f16x8 FAl1 = *(const f16x8*)&hbuf[P][1][adA0 + 32];
        f16x8 FBh0 = *(const f16x8*)&hbuf[P][0][adA0 + 16*HS];
        f16x8 FBh1 = *(const f16x8*)&hbuf[P][0][adA0 + 16*HS + 32];
        f16x8 FBl0 = *(const f16x8*)&hbuf[P][1][adA0 + 16*HS];
        f16x8 FBl1 = *(const f16x8*)&hbuf[P][1][adA0 + 16*HS + 32];
        #pragma unroll
        for (int mt = 0; mt < 2; ++mt) {
            f32x4 a = {bhc,bhc,bhc,bhc}, b = {0.f,0.f,0.f,0.f};
            if (mt == 0) {
                a = __builtin_amdgcn_mfma_f32_16x16x32_f16(FAh0, HBh[0], a, 0,0,0);
                a = __builtin_amdgcn_mfma_f32_16x16x32_f16(FAh1, HBh[1], a, 0,0,0);
                b = __builtin_amdgcn_mfma_f32_16x16x32_f16(FAh0, HBl[0], b, 0,0,0);
                b = __builtin_amdgcn_mfma_f32_16x16x32_f16(FAl0, HBh[0], b, 0,0,0);
                b = __builtin_amdgcn_mfma_f32_16x16x32_f16(FAh1, HBl[1], b, 0,0,0);
                b = __builtin_amdgcn_mfma_f32_16x16x32_f16(FAl1, HBh[1], b, 0,0,0);
            } else {
                a = __builtin_amdgcn_mfma_f32_16x16x32_f16(FBh0, HBh[0], a, 0,0,0);
                a = __builtin_amdgcn_mfma_f32_16x16x32_f16(FBh1, HBh[1], a, 0,0,0);
                b = __builtin_amdgcn_mfma_f32_16x16x32_f16(FBh0, HBl[0], b, 0,0,0);
                b = __builtin_amdgcn_mfma_f32_16x16x32_f16(FBl0, HBh[0], b, 0,0,0);
                b = __builtin_amdgcn_mfma_f32_16x16x32_f16(FBh1, HBl[1], b, 0,0,0);
                b = __builtin_amdgcn_mfma_f32_16x16x32_f16(FBl1, HBh[1], b, 0,0,0);
            }
            #pragma unroll
            for (int r = 0; r < 4; ++r) {
                float fv = __builtin_fmaf(INV2K, b[r], a[r]);
                zreg[mt][r][0] = __builtin_fmaf(dtv, bpermf(sa0, fv), zreg[mt][r][0]);
                zreg[mt][r][1] = __builtin_fmaf(dtv, bpermf(sa1, fv), zreg[mt][r][1]);
                zreg[mt][r][2] = __builtin_fmaf(dtv, bpermf(sa2, fv), zreg[mt][r][2]);
            }
        }
        #pragma unroll
        for (int mt = 0; mt < 2; ++mt)
            #pragma unroll
            for (int c = 0; c < 3; ++c)
                if (w == mt && c16 == c) {
                    o0[0] = zreg[mt][0][c]; o1[0] = zreg[mt][1][c];
                    o2[0] = zreg[mt][2][c]; o3[0] = zreg[mt][3][c];
                }
    }
#undef STEP
#undef STEPFULL
#undef GATE0
#undef GATE1
#undef GATE
}

extern "C" void kernel_launch(void* const* d_in, const int* in_sizes, int n_in,
                              void* d_out, int out_size, void* d_ws, size_t ws_size,
                              hipStream_t stream) {
    const float* z0    = (const float*)d_in[0];
    const float* dtp   = (const float*)d_in[1];
    const int*   steps = (const int*)  d_in[2];
    const float* Wih   = (const float*)d_in[3];
    const float* Whh   = (const float*)d_in[4];
    const float* bih   = (const float*)d_in[5];
    const float* bhh   = (const float*)d_in[6];
    const float* Whead = (const float*)d_in[7];
    const float* bhead = (const float*)d_in[8];
    float* out = (float*)d_out;

    const int B = in_sizes[0] / 3;          // 16384
    const int nblk = B / MELEM;             // 512 blocks x 256 threads = 2 blocks/CU

    hipLaunchKernelGGL(gru_mfma_kernel, dim3(nblk), dim3(256), 0, stream,
                       z0, dtp, steps, Wih, Whh, bih, bhh, Whead, bhead, out);
}

// Round 14
// 4463.329 us; speedup vs baseline: 1.1589x; 1.0008x over previous
//
#include <hip/hip_runtime.h>

typedef _Float16 f16x8 __attribute__((ext_vector_type(8)));
typedef float f32x4 __attribute__((ext_vector_type(4)));

#define LOG2E 1.44269504088896340736f
#define MELEM 32          // batch elems per block (2 M-tiles of 16)
#define HS 72             // f16 stride of h LDS rows (16B-aligned, bank-spread)
#define INV2K 4.8828125e-4f   // 2^-11
#define SC2K  2048.0f         // 2^11

__device__ __forceinline__ float bpermf(int sa, float v) {
    return __builtin_bit_cast(float,
        __builtin_amdgcn_ds_bpermute(sa, __builtin_bit_cast(int, v)));
}

// barrier that waits ONLY on LDS (lgkm), not on in-flight global traj stores
#define LDS_BARRIER() asm volatile("s_waitcnt lgkmcnt(0)\n\ts_barrier" ::: "memory")

__global__ __launch_bounds__(256, 2)
void gru_mfma_kernel(const float* __restrict__ z0,
                     const float* __restrict__ dtp,
                     const int* __restrict__ stepsp,
                     const float* __restrict__ Wih,
                     const float* __restrict__ Whh,
                     const float* __restrict__ bih,
                     const float* __restrict__ bhh,
                     const float* __restrict__ Whead,
                     const float* __restrict__ bhead,
                     float* __restrict__ out)
{
    // [pingpong][part hi/lo][elem*HS + unit], fp16 2-way split of h
    __shared__ _Float16 hbuf[2][2][MELEM*HS];

    const int tid = threadIdx.x;
    const int w   = tid >> 6;       // wave 0..3 -> unit range [16w,16w+16)
    const int l   = tid & 63;
    const int c16 = l & 15;
    const int g   = l >> 4;         // 0..3
    const int unit = 16*w + c16;

    const float dtv = dtp[0];
    const int nsteps = stepsp[0];
    const size_t T3 = (size_t)(nsteps + 1) * 3;
    const long blk = blockIdx.x;

    // ---- B-fragments of W_hh: fp16 hi + 2^11-scaled lo, LOG2E-prescaled ----
    // gates r,u scaled by LOG2E; gate n by 2*LOG2E (tanh's 2x folded in)
    f16x8 WBh[3][2], WBl[3][2];
    #pragma unroll
    for (int gate = 0; gate < 3; ++gate) {
        const float gs = (gate == 2) ? 2.f*LOG2E : LOG2E;
        const float* row = Whh + (size_t)(gate*64 + unit) * 64;
        #pragma unroll
        for (int kk = 0; kk < 2; ++kk) {
            const float* p = row + 32*kk + 8*g;
            f16x8 bh_, bl_;
            #pragma unroll
            for (int j = 0; j < 8; ++j) {
                float x = gs * p[j];
                _Float16 hi = (_Float16)x;
                bh_[j] = hi;
                bl_[j] = (_Float16)((x - (float)hi) * SC2K);
            }
            WBh[gate][kk] = bh_;
            WBl[gate][kk] = bl_;
        }
    }
    // ---- head B-fragments in regs (cols >= 3 zero), plain scale ----
    f16x8 HBh[2], HBl[2];
    {
        f16x8 zf = {0,0,0,0,0,0,0,0};
        HBh[0]=zf; HBh[1]=zf; HBl[0]=zf; HBl[1]=zf;
        if (c16 < 3) {
            #pragma unroll
            for (int kk = 0; kk < 2; ++kk) {
                const float* p = Whead + (size_t)c16*64 + 32*kk + 8*g;
                f16x8 bh_, bl_;
                #pragma unroll
                for (int j = 0; j < 8; ++j) {
                    float x = p[j];
                    _Float16 hi = (_Float16)x;
                    bh_[j] = hi;
                    bl_[j] = (_Float16)((x - (float)hi) * SC2K);
                }
                HBh[kk] = bh_; HBl[kk] = bl_;
            }
        }
    }

    // ---- per-lane scalar weights / biases (prescaled) ----
    const float wir0 = LOG2E*Wih[(0*64+unit)*3+0], wir1 = LOG2E*Wih[(0*64+unit)*3+1], wir2 = LOG2E*Wih[(0*64+unit)*3+2];
    const float wiu0 = LOG2E*Wih[(1*64+unit)*3+0], wiu1 = LOG2E*Wih[(1*64+unit)*3+1], wiu2 = LOG2E*Wih[(1*64+unit)*3+2];
    const float win0 = 2.f*LOG2E*Wih[(2*64+unit)*3+0], win1 = 2.f*LOG2E*Wih[(2*64+unit)*3+1], win2 = 2.f*LOG2E*Wih[(2*64+unit)*3+2];
    const float br   = LOG2E*(bih[0*64+unit] + bhh[0*64+unit]);
    const float bu   = LOG2E*(bih[1*64+unit] + bhh[1*64+unit]);
    const float bin_ = 2.f*LOG2E*bih[2*64+unit];
    const float bhn  = 2.f*LOG2E*bhh[2*64+unit];
    float bhc = 0.f;
    if (c16 < 3) bhc = bhead[c16];

    // ---- z replicated in registers on every lane (all indices static) ----
    float zreg[2][4][3];
    #pragma unroll
    for (int mt = 0; mt < 2; ++mt)
        #pragma unroll
        for (int r = 0; r < 4; ++r)
            #pragma unroll
            for (int c = 0; c < 3; ++c)
                zreg[mt][r][c] = z0[(size_t)(blk*MELEM + mt*16 + 4*g + r)*3 + c];

    // ---- persistent traj cursors (designated lanes: w<2 && c16<3) ----
    float* o0 = out; float* o1 = out; float* o2 = out; float* o3 = out;
    if (w < 2 && c16 < 3) {
        size_t e0 = (size_t)(blk*MELEM + w*16 + 4*g);
        o0 = out + (e0+0)*T3 + c16;
        o1 = out + (e0+1)*T3 + c16;
        o2 = out + (e0+2)*T3 + c16;
        o3 = out + (e0+3)*T3 + c16;
    }
    // t=0 row (static zreg indices via unrolled predication)
    #pragma unroll
    for (int mt = 0; mt < 2; ++mt)
        #pragma unroll
        for (int c = 0; c < 3; ++c)
            if (w == mt && c16 == c) {
                o0[0] = zreg[mt][0][c]; o1[0] = zreg[mt][1][c];
                o2[0] = zreg[mt][2][c]; o3[0] = zreg[mt][3][c];
            }
    if (w < 2 && c16 < 3) { o0 += 3; o1 += 3; o2 += 3; o3 += 3; }  // -> t=1

    // hoisted bpermute byte-addresses
    const int sa0 = (l & 48) << 2;
    const int sa1 = sa0 + 4;
    const int sa2 = sa0 + 8;

    // step-invariant LDS element offset for A-fragments (row = c16)
    const int adA0 = c16*HS + 8*g;

    // ---- zero h buffer 0 (h_0 = 0) ----
    {
        uint* hz = (uint*)&hbuf[0][0][0];
        for (int i = tid; i < MELEM*HS; i += 256) hz[i] = 0u;
    }

    float hC[2][4] = {{0,0,0,0},{0,0,0,0}};

    __syncthreads();

#define GATE0(GT, GR, BIAS) do {                                                 \
    f32x4 a1 = {BIAS,BIAS,BIAS,BIAS}, a2 = {0.f,0.f,0.f,0.f};                    \
    a1 = __builtin_amdgcn_mfma_f32_16x16x32_f16(FAh0, WBh[GT][0], a1, 0,0,0);    \
    a2 = __builtin_amdgcn_mfma_f32_16x16x32_f16(FAh0, WBl[GT][0], a2, 0,0,0);    \
    a2 = __builtin_amdgcn_mfma_f32_16x16x32_f16(FAl0, WBh[GT][0], a2, 0,0,0);    \
    a1 = __builtin_amdgcn_mfma_f32_16x16x32_f16(FAh1, WBh[GT][1], a1, 0,0,0);    \
    a2 = __builtin_amdgcn_mfma_f32_16x16x32_f16(FAh1, WBl[GT][1], a2, 0,0,0);    \
    a2 = __builtin_amdgcn_mfma_f32_16x16x32_f16(FAl1, WBh[GT][1], a2, 0,0,0);    \
    _Pragma("unroll")                                                            \
    for (int rr = 0; rr < 4; ++rr) GR[rr] = __builtin_fmaf(INV2K, a2[rr], a1[rr]); \
} while (0)
#define GATE1(GT, GR, BIAS) do {                                                 \
    f32x4 a1 = {BIAS,BIAS,BIAS,BIAS}, a2 = {0.f,0.f,0.f,0.f};                    \
    a1 = __builtin_amdgcn_mfma_f32_16x16x32_f16(FBh0, WBh[GT][0], a1, 0,0,0);    \
    a2 = __builtin_amdgcn_mfma_f32_16x16x32_f16(FBh0, WBl[GT][0], a2, 0,0,0);    \
    a2 = __builtin_amdgcn_mfma_f32_16x16x32_f16(FBl0, WBh[GT][0], a2, 0,0,0);    \
    a1 = __builtin_amdgcn_mfma_f32_16x16x32_f16(FBh1, WBh[GT][1], a1, 0,0,0);    \
    a2 = __builtin_amdgcn_mfma_f32_16x16x32_f16(FBh1, WBl[GT][1], a2, 0,0,0);    \
    a2 = __builtin_amdgcn_mfma_f32_16x16x32_f16(FBl1, WBh[GT][1], a2, 0,0,0);    \
    _Pragma("unroll")                                                            \
    for (int rr = 0; rr < 4; ++rr) GR[rr] = __builtin_fmaf(INV2K, a2[rr], a1[rr]); \
} while (0)

#define STEP(P, DOZ) do {                                                        \
    f16x8 FAh0 = *(const f16x8*)&hbuf[P][0][adA0];                               \
    f16x8 FAh1 = *(const f16x8*)&hbuf[P][0][adA0 + 32];                          \
    f16x8 FAl0 = *(const f16x8*)&hbuf[P][1][adA0];                               \
    f16x8 FAl1 = *(const f16x8*)&hbuf[P][1][adA0 + 32];                          \
    f16x8 FBh0 = *(const f16x8*)&hbuf[P][0][adA0 + 16*HS];                       \
    f16x8 FBh1 = *(const f16x8*)&hbuf[P][0][adA0 + 16*HS + 32];                  \
    f16x8 FBl0 = *(const f16x8*)&hbuf[P][1][adA0 + 16*HS];                       \
    f16x8 FBl1 = *(const f16x8*)&hbuf[P][1][adA0 + 16*HS + 32];                  \
    if (DOZ) {                                                                   \
        f32x4 ha[2], hb[2];                                                      \
        _Pragma("unroll")                                                        \
        for (int mt = 0; mt < 2; ++mt) {                                         \
            f32x4 a = {bhc,bhc,bhc,bhc}, b = {0.f,0.f,0.f,0.f};                  \
            if (mt == 0) {                                                       \
                a = __builtin_amdgcn_mfma_f32_16x16x32_f16(FAh0, HBh[0], a, 0,0,0); \
                a = __builtin_amdgcn_mfma_f32_16x16x32_f16(FAh1, HBh[1], a, 0,0,0); \
                b = __builtin_amdgcn_mfma_f32_16x16x32_f16(FAh0, HBl[0], b, 0,0,0); \
                b = __builtin_amdgcn_mfma_f32_16x16x32_f16(FAl0, HBh[0], b, 0,0,0); \
                b = __builtin_amdgcn_mfma_f32_16x16x32_f16(FAh1, HBl[1], b, 0,0,0); \
                b = __builtin_amdgcn_mfma_f32_16x16x32_f16(FAl1, HBh[1], b, 0,0,0); \
            } else {                                                             \
                a = __builtin_amdgcn_mfma_f32_16x16x32_f16(FBh0, HBh[0], a, 0,0,0); \
                a = __builtin_amdgcn_mfma_f32_16x16x32_f16(FBh1, HBh[1], a, 0,0,0); \
                b = __builtin_amdgcn_mfma_f32_16x16x32_f16(FBh0, HBl[0], b, 0,0,0); \
                b = __builtin_amdgcn_mfma_f32_16x16x32_f16(FBl0, HBh[0], b, 0,0,0); \
                b = __builtin_amdgcn_mfma_f32_16x16x32_f16(FBh1, HBl[1], b, 0,0,0); \
                b = __builtin_amdgcn_mfma_f32_16x16x32_f16(FBl1, HBh[1], b, 0,0,0); \
            }                                                                    \
            ha[mt] = a; hb[mt] = b;                                              \
        }                                                                        \
        _Pragma("unroll")                                                        \
        for (int mt = 0; mt < 2; ++mt)                                           \
            _Pragma("unroll")                                                    \
            for (int r = 0; r < 4; ++r) {                                        \
                float fv = __builtin_fmaf(INV2K, hb[mt][r], ha[mt][r]);          \
                zreg[mt][r][0] = __builtin_fmaf(dtv, bpermf(sa0, fv), zreg[mt][r][0]); \
                zreg[mt][r][1] = __builtin_fmaf(dtv, bpermf(sa1, fv), zreg[mt][r][1]); \
                zreg[mt][r][2] = __builtin_fmaf(dtv, bpermf(sa2, fv), zreg[mt][r][2]); \
            }                                                                    \
        _Pragma("unroll")                                                        \
        for (int mt = 0; mt < 2; ++mt)                                           \
            _Pragma("unroll")                                                    \
            for (int c = 0; c < 3; ++c)                                          \
                if (w == mt && c16 == c) {                                       \
                    o0[0] = zreg[mt][0][c]; o1[0] = zreg[mt][1][c];              \
                    o2[0] = zreg[mt][2][c]; o3[0] = zreg[mt][3][c];              \
                }                                                                \
        if (w < 2 && c16 < 3) { o0 += 3; o1 += 3; o2 += 3; o3 += 3; }            \
    }                                                                            \
    _Pragma("unroll")                                                            \
    for (int mt = 0; mt < 2; ++mt) {                                             \
        f32x4 gr0, gr1, gr2;                                                     \
        if (mt == 0) {                                                           \
            GATE0(0, gr0, br); GATE0(1, gr1, bu); GATE0(2, gr2, bhn);            \
        } else {                                                                 \
            GATE1(0, gr0, br); GATE1(1, gr1, bu); GATE1(2, gr2, bhn);            \
        }                                                                        \
        _Pragma("unroll")                                                        \
        for (int r = 0; r < 4; ++r) {                                            \
            float z0v = zreg[mt][r][0], z1v = zreg[mt][r][1], z2v = zreg[mt][r][2]; \
            float ar  = __builtin_fmaf(wir0, z0v, __builtin_fmaf(wir1, z1v,      \
                        __builtin_fmaf(wir2, z2v, gr0[r])));                     \
            float au  = __builtin_fmaf(wiu0, z0v, __builtin_fmaf(wiu1, z1v,      \
                        __builtin_fmaf(wiu2, z2v, gr1[r])));                     \
            float ain = __builtin_fmaf(win0, z0v, __builtin_fmaf(win1, z1v,      \
                        __builtin_fmaf(win2, z2v, bin_)));                       \
            float rg = __builtin_amdgcn_rcpf(1.f + __builtin_amdgcn_exp2f(-ar)); \
            float ug = __builtin_amdgcn_rcpf(1.f + __builtin_amdgcn_exp2f(-au)); \
            float xs = __builtin_fmaf(rg, gr2[r], ain);                          \
            float ng = __builtin_fmaf(-2.f,                                      \
                __builtin_amdgcn_rcpf(1.f + __builtin_amdgcn_exp2f(xs)), 1.f);   \
            float hn = __builtin_fmaf(ug, hC[mt][r] - ng, ng);                   \
            hC[mt][r] = hn;                                                      \
            _Float16 hi = (_Float16)hn;                                          \
            _Float16 lo = (_Float16)((hn - (float)hi) * SC2K);                   \
            hbuf[(P)^1][0][(mt*16 + 4*g + r)*HS + unit] = hi;                    \
            hbuf[(P)^1][1][(mt*16 + 4*g + r)*HS + unit] = lo;                    \
        }                                                                        \
    }                                                                            \
    LDS_BARRIER();                                                               \
} while (0)

    // ---- main loop: peel t=0, then pairs (compile-time ping-pong) ----
    STEP(0, false);
    int t = 1;
    for (; t + 1 < nsteps; t += 2) {
        STEP(1, true);
        STEP(0, true);
    }
    if (t < nsteps) { STEP(1, true); ++t; }

    // ---- epilogue: z(nsteps) from head over h(nsteps) ----
    {
        const int P = nsteps & 1;
        f16x8 FAh0 = *(const f16x8*)&hbuf[P][0][adA0];
        f16x8 FAh1 = *(const f16x8*)&hbuf[P][0][adA0 + 32];
        f16x8 FAl0 = *(const f16x8*)&hbuf[P][1][adA0];
        f16x8 FAl1 = *(const f16x8*)&hbuf[P][1][adA0 + 32];
        f16x8 FBh0 = *(const f16x8*)&hbuf[P][0][adA0 + 16*HS];
        f16x8 FBh1 = *(const f16x8*)&hbuf[P][0][adA0 + 16*HS + 32];
        f16x8 FBl0 = *(const f16x8*)&hbuf[P][1][adA0 + 16*HS];
        f16x8 FBl1 = *(const f16x8*)&hbuf[P][1][adA0 + 16*HS + 32];
        #pragma unroll
        for (int mt = 0; mt < 2; ++mt) {
            f32x4 a = {bhc,bhc,bhc,bhc}, b = {0.f,0.f,0.f,0.f};
            if (mt == 0) {
                a = __builtin_amdgcn_mfma_f32_16x16x32_f16(FAh0, HBh[0], a, 0,0,0);
                a = __builtin_amdgcn_mfma_f32_16x16x32_f16(FAh1, HBh[1], a, 0,0,0);
                b = __builtin_amdgcn_mfma_f32_16x16x32_f16(FAh0, HBl[0], b, 0,0,0);
                b = __builtin_amdgcn_mfma_f32_16x16x32_f16(FAl0, HBh[0], b, 0,0,0);
                b = __builtin_amdgcn_mfma_f32_16x16x32_f16(FAh1, HBl[1], b, 0,0,0);
                b = __builtin_amdgcn_mfma_f32_16x16x32_f16(FAl1, HBh[1], b, 0,0,0);
            } else {
                a = __builtin_amdgcn_mfma_f32_16x16x32_f16(FBh0, HBh[0], a, 0,0,0);
                a = __builtin_amdgcn_mfma_f32_16x16x32_f16(FBh1, HBh[1], a, 0,0,0);
                b = __builtin_amdgcn_mfma_f32_16x16x32_f16(FBh0, HBl[0], b, 0,0,0);
                b = __builtin_amdgcn_mfma_f32_16x16x32_f16(FBl0, HBh[0], b, 0,0,0);
                b = __builtin_amdgcn_mfma_f32_16x16x32_f16(FBh1, HBl[1], b, 0,0,0);
                b = __builtin_amdgcn_mfma_f32_16x16x32_f16(FBl1, HBh[1], b, 0,0,0);
            }
            #pragma unroll
            for (int r = 0; r < 4; ++r) {
                float fv = __builtin_fmaf(INV2K, b[r], a[r]);
                zreg[mt][r][0] = __builtin_fmaf(dtv, bpermf(sa0, fv), zreg[mt][r][0]);
                zreg[mt][r][1] = __builtin_fmaf(dtv, bpermf(sa1, fv), zreg[mt][r][1]);
                zreg[mt][r][2] = __builtin_fmaf(dtv, bpermf(sa2, fv), zreg[mt][r][2]);
            }
        }
        #pragma unroll
        for (int mt = 0; mt < 2; ++mt)
            #pragma unroll
            for (int c = 0; c < 3; ++c)
                if (w == mt && c16 == c) {
                    o0[0] = zreg[mt][0][c]; o1[0] = zreg[mt][1][c];
                    o2[0] = zreg[mt][2][c]; o3[0] = zreg[mt][3][c];
                }
    }
#undef STEP
#undef GATE0
#undef GATE1
}

extern "C" void kernel_launch(void* const* d_in, const int* in_sizes, int n_in,
                              void* d_out, int out_size, void* d_ws, size_t ws_size,
                              hipStream_t stream) {
    const float* z0    = (const float*)d_in[0];
    const float* dtp   = (const float*)d_in[1];
    const int*   steps = (const int*)  d_in[2];
    const float* Wih   = (const float*)d_in[3];
    const float* Whh   = (const float*)d_in[4];
    const float* bih   = (const float*)d_in[5];
    const float* bhh   = (const float*)d_in[6];
    const float* Whead = (const float*)d_in[7];
    const float* bhead = (const float*)d_in[8];
    float* out = (float*)d_out;

    const int B = in_sizes[0] / 3;          // 16384
    const int nblk = B / MELEM;             // 512 blocks x 256 threads = 2 blocks/CU

    hipLaunchKernelGGL(gru_mfma_kernel, dim3(nblk), dim3(256), 0, stream,
                       z0, dtp, steps, Wih, Whh, bih, bhh, Whead, bhead, out);
}